// Round 16
// baseline (46.790 us; speedup 1.0000x reference)
//
#include <hip/hip_runtime.h>
#include <hip/hip_bf16.h>
#include <math.h>

#define SEQ 8192
#define NSYM 1000000
#define EPSC 1e-6f

#define NCHUNK 1024
#define KEEPG 2             // kept groups per chunk (8 steps)
#define WARMG 4             // warmup groups (16 steps), clamped at t=0
#define NG 6                // groups scanned per chunk (24 steps)
#define NBLK 256
#define CHPB 4              // chunks per block (one per wave)

typedef float v2f __attribute__((ext_vector_type(2)));
typedef float v4f __attribute__((ext_vector_type(4)));

__device__ __forceinline__ float rcp_(float x){ return __builtin_amdgcn_rcpf(x); }
__device__ __forceinline__ float exp2f_(float x){ return __builtin_amdgcn_exp2f(x); }
__device__ __forceinline__ float sigf(float x){ return rcp_(1.f + exp2f_(-1.44269504f*x)); }
__device__ __forceinline__ float tanhf_(float x){
  float e = exp2f_(2.88539008f*fabsf(x));
  float t = 1.f - 2.f*rcp_(e + 1.f);
  return copysignf(t, x);
}
__device__ __forceinline__ float softplusf_(float x){
  return fmaxf(x, 0.f) + log1pf(__expf(-fabsf(x)));
}
__device__ __forceinline__ float rdlane(float v, int lane){
  return __builtin_bit_cast(float, __builtin_amdgcn_readlane(__builtin_bit_cast(int, v), lane));
}
__device__ __forceinline__ float xchg32(float v){
  return __shfl_xor(v, 32, 64);
}

// ---------------- single fused kernel: scan (all blocks) + DNC tail (last block) ----------------
__global__ __launch_bounds__(256) void k_all(
    const int* __restrict__ x, const float* __restrict__ emb,
    const float* __restrict__ Wih, const float* __restrict__ bih,
    const float* __restrict__ bhh, const float* __restrict__ Whh,
    const float* __restrict__ ctrl_Wih, const float* __restrict__ ctrl_bih, const float* __restrict__ ctrl_bhh,
    const float* __restrict__ w_alloc_W, const float* __restrict__ w_alloc_b,
    const float* __restrict__ w_gate_W,  const float* __restrict__ w_gate_b,
    const float* __restrict__ w_erase_W, const float* __restrict__ w_erase_b,
    const float* __restrict__ w_add_W,   const float* __restrict__ w_add_b,
    const float* __restrict__ r_key_W,   const float* __restrict__ r_key_b,
    const float* __restrict__ r_beta_W,  const float* __restrict__ r_beta_b,
    const float* __restrict__ r_mode_W,  const float* __restrict__ r_mode_b,
    const float* __restrict__ out_W,     const float* __restrict__ out_b,
    const float* __restrict__ lin_W,     const float* __restrict__ lin_b,
    const float* __restrict__ act_W,     const float* __restrict__ act_b,
    float* __restrict__ spart, int* __restrict__ counter,
    float* __restrict__ out){
  const int u    = threadIdx.x;            // 0..255
  const int B    = blockIdx.x;             // 0..255
  const int w    = u >> 6;                 // wave id
  const int lane = u & 63;
  const int b    = B*CHPB + w;             // chunk id 0..1023
  const int half = lane >> 5;
  const int j    = lane & 31;
  const int jj   = (j < 20) ? j : 0;

  const int rowA = half ? (20+jj) : jj;        // f : i
  const int rowB = half ? (60+jj) : (40+jj);   // o : g

  const int kept0 = b*KEEPG;                                // first kept group
  const int g0    = (kept0 >= WARMG) ? (kept0 - WARMG) : 0; // clamped start
  const int b0k   = B*CHPB*KEEPG;                           // block's first kept group
  const int gbase = (b0k >= WARMG) ? (b0k - WARMG) : 0;     // block staging base

  // ---- shared: scan staging + DNC-tail workspace ----
  __shared__ int   xs_i[12*4];
  __shared__ float xe_s[12*4][20];         // 12 groups x 4 steps, 80B rows
  __shared__ float part_s[256][20];
  __shared__ float x4_s[20], h_s[64], rkey_s[64], rbeta_s[4], rknorm_s[4];
  __shared__ float erase_s[16], add_s[16], mode_s[12], wlw_s[16];
  __shared__ float mem_s[256], mnorm_s[16], wlr_s[64], rv_s[64], x4b_s[20], x5_s[20];
  __shared__ float scal_s[2];
  __shared__ int   flag_s;

  if (u < 48) xs_i[u] = x[gbase*4 + u];
  __syncthreads();
  #pragma unroll
  for (int it=0; it<4; it++){              // 960 elements / 256 threads
    int idx = u + it*256;
    if (idx < 960){
      int r = idx/20, k = idx%20;
      int sym = xs_i[r];
      xe_s[r][k] = (sym == NSYM) ? 0.f : emb[(size_t)sym*20 + k];
    }
  }

  // paired weights (per lane)
  v2f W0[5], W1[5], W2[5], W3[5], WIF[20];
  #pragma unroll
  for (int k=0;k<5;k++){
    W0[k] = (v2f){Whh[rowA*20+k   ], Whh[rowB*20+k   ]};
    W1[k] = (v2f){Whh[rowA*20+5+k ], Whh[rowB*20+5+k ]};
    W2[k] = (v2f){Whh[rowA*20+10+k], Whh[rowB*20+10+k]};
    W3[k] = (v2f){Whh[rowA*20+15+k], Whh[rowB*20+15+k]};
  }
  #pragma unroll
  for (int k=0;k<20;k++) WIF[k] = (v2f){Wih[rowA*20+k], Wih[rowB*20+k]};
  const v2f bAB = (v2f){bih[rowA]+bhh[rowA], bih[rowB]+bhh[rowB]};

  __syncthreads();

  // inline A for this wave's 6 groups (rows g0-gbase+g in xe_s)
  v2f AG[NG][4];
  {
    const int r0 = g0 - gbase;
    #pragma unroll
    for (int g=0; g<NG; g++){
      #pragma unroll
      for (int tl=0; tl<4; tl++){
        v2f acc = bAB;
        #pragma unroll
        for (int q=0;q<5;q++){
          const float4 xr = *(const float4*)&xe_s[(r0+g)*4+tl][q*4];
          acc = __builtin_elementwise_fma((v2f){xr.x,xr.x}, WIF[q*4+0], acc);
          acc = __builtin_elementwise_fma((v2f){xr.y,xr.y}, WIF[q*4+1], acc);
          acc = __builtin_elementwise_fma((v2f){xr.z,xr.z}, WIF[q*4+2], acc);
          acc = __builtin_elementwise_fma((v2f){xr.w,xr.w}, WIF[q*4+3], acc);
        }
        AG[g][tl] = acc;
      }
    }
  }

  const float mtr = half ? -1.44269504f : 2.88539008f;
  float h=0.f, c=0.f, s=0.f;

  auto stepf = [&](v2f pab, float kp){
    v2f A0 = pab, A1 = (v2f){0.f,0.f}, A2v = (v2f){0.f,0.f}, A3 = (v2f){0.f,0.f};
    #pragma unroll
    for (int k=0;k<5;k++){
      float h0 = rdlane(h, 32+k);
      float h1 = rdlane(h, 37+k);
      float h2 = rdlane(h, 42+k);
      float h3 = rdlane(h, 47+k);
      A0  = __builtin_elementwise_fma((v2f){h0,h0}, W0[k], A0);
      A1  = __builtin_elementwise_fma((v2f){h1,h1}, W1[k], A1);
      A2v = __builtin_elementwise_fma((v2f){h2,h2}, W2[k], A2v);
      A3  = __builtin_elementwise_fma((v2f){h3,h3}, W3[k], A3);
    }
    v2f S = (A0+A1) + (A2v+A3);
    float s0 = sigf(S.x);               // halfA: sig(i)   halfB: sig(f)
    float xx = half ? S.y : fabsf(S.y);
    float e  = exp2f_(mtr*xx);          // halfA: e^{2|g|}  halfB: e^{-o}
    float z  = rcp_(1.f + e);
    float u2 = half ? z                                  // sig(o)
                    : copysignf(fmaf(-2.f, z, 1.f), S.y); // tanh(g)
    float send = s0 * u2;               // halfA payload: sig(i)*tanh(g)
    float recv = xchg32(send);
    c = fmaf(s0, c, recv);              // halfB: c = sig(f)*c + sig(i)*tanh(g)
    h = u2 * tanhf_(c);                 // halfB: h = sig(o)*tanh(c)
    s = fmaf(kp, h, s);                 // accumulate only in kept region
  };

  #pragma unroll
  for (int g=0; g<NG; g++){
    int ag = g0 + g;
    float kp = (ag >= kept0 && ag < kept0+KEEPG) ? 1.f : 0.f;
    stepf(AG[g][0], kp);
    stepf(AG[g][1], kp);
    stepf(AG[g][2], kp);
    stepf(AG[g][3], kp);
  }

  if (lane >= 32 && lane < 52) spart[b*20 + (lane-32)] = s;

  // ---- device-scope release + last-block election ----
  __threadfence();                          // release this thread's spart stores
  __syncthreads();
  if (u == 0) flag_s = atomicAdd(counter, 1);
  __syncthreads();
  if (flag_s != NBLK-1) return;             // all but the last block exit
  __threadfence();                          // acquire: see all blocks' spart

  // ================= DNC tail (256 threads, one block) =================
  // phase 1: each thread sums 4 chunks via 20 independent float4 loads
  {
    const v4f* sp4 = (const v4f*)spart;
    v4f acc[5];
    #pragma unroll
    for (int q=0;q<5;q++) acc[q] = (v4f){0.f,0.f,0.f,0.f};
    #pragma unroll
    for (int cc=0;cc<4;cc++){
      #pragma unroll
      for (int q=0;q<5;q++) acc[q] += sp4[(u*4+cc)*5 + q];
    }
    #pragma unroll
    for (int q=0;q<5;q++){
      part_s[u][q*4+0] = acc[q].x;
      part_s[u][q*4+1] = acc[q].y;
      part_s[u][q*4+2] = acc[q].z;
      part_s[u][q*4+3] = acc[q].w;
    }
  }
  __syncthreads();
  if (u < 20){
    float t = 0.f;
    #pragma unroll
    for (int k=0;k<256;k++) t += part_s[k][u];
    x4_s[u] = t;
  }
  __syncthreads();

  // controller LSTMCell: input = cat(x4, zeros(64)); h0=c0=0 (wave 0)
  if (u < 64){
    float gi = ctrl_bih[u]      + ctrl_bhh[u];
    float gG = ctrl_bih[128+u]  + ctrl_bhh[128+u];
    float go = ctrl_bih[192+u]  + ctrl_bhh[192+u];
    #pragma unroll
    for (int k=0;k<20;k++){
      float xk = x4_s[k];
      gi = fmaf(xk, ctrl_Wih[(0  +u)*84+k], gi);
      gG = fmaf(xk, ctrl_Wih[(128+u)*84+k], gG);
      go = fmaf(xk, ctrl_Wih[(192+u)*84+k], go);
    }
    float cc2 = sigf(gi)*tanhf_(gG);
    float hh = sigf(go)*tanhf_(cc2);
    hh = fminf(fmaxf(hh, -20.f), 20.f);
    h_s[u] = hh;
  }
  __syncthreads();

  // head linears over h, spread across the 4 waves
  if (u < 64){                                   // wave 0: rkey
    float d = r_key_b[u];
    #pragma unroll
    for (int k=0;k<64;k++) d = fmaf(h_s[k], r_key_W[u*64+k], d);
    rkey_s[u] = tanhf_(d);
  } else if (u >= 64 && u < 80){                 // wave 1: erase
    int e = u-64; float d = w_erase_b[e];
    #pragma unroll
    for (int k=0;k<64;k++) d = fmaf(h_s[k], w_erase_W[e*64+k], d);
    erase_s[e] = sigf(d);
  } else if (u >= 128 && u < 144){               // wave 2: add
    int a = u-128; float d = w_add_b[a];
    #pragma unroll
    for (int k=0;k<64;k++) d = fmaf(h_s[k], w_add_W[a*64+k], d);
    add_s[a] = tanhf_(d);
  } else if (u >= 144 && u < 156){               // wave 2: mode
    int m = u-144; float d = r_mode_b[m];
    #pragma unroll
    for (int k=0;k<64;k++) d = fmaf(h_s[k], r_mode_W[m*64+k], d);
    mode_s[m] = d;
  } else if (u >= 192 && u < 196){               // wave 3: rbeta
    int r = u-192; float d = r_beta_b[r];
    #pragma unroll
    for (int k=0;k<64;k++) d = fmaf(h_s[k], r_beta_W[r*64+k], d);
    rbeta_s[r] = softplusf_(d);
  } else if (u == 196){                          // wave 3: alloc gate
    float d = w_alloc_b[0];
    #pragma unroll
    for (int k=0;k<64;k++) d = fmaf(h_s[k], w_alloc_W[k], d);
    scal_s[0] = sigf(d);
  } else if (u == 197){                          // wave 3: write gate
    float d = w_gate_b[0];
    #pragma unroll
    for (int k=0;k<64;k++) d = fmaf(h_s[k], w_gate_W[k], d);
    scal_s[1] = sigf(d);
  }
  __syncthreads();

  const float alloc_gate = scal_s[0], write_gate = scal_s[1];

  if (u < 16){
    float cp = 1.f;
    for (int i2=0;i2<u;i2++) cp *= EPSC;
    float alloc = (1.f-EPSC)*cp;
    wlw_s[u] = write_gate*(alloc_gate*alloc + (1.f-alloc_gate)*0.0625f);
  }
  if (u >= 32 && u < 36){
    int r = u-32;
    float s2 = 0.f;
    #pragma unroll
    for (int w2=0;w2<16;w2++) s2 = fmaf(rkey_s[r*16+w2], rkey_s[r*16+w2], s2);
    rknorm_s[r] = sqrtf(s2) + EPSC;
  }
  __syncthreads();

  {
    int n = u>>4, w2 = u&15;
    float wlw = wlw_s[n];
    mem_s[u] = 1e-6f*(1.f - wlw*erase_s[w2]) + wlw*add_s[w2];
  }
  __syncthreads();
  if (u < 16){
    float s2 = 0.f;
    #pragma unroll
    for (int w2=0;w2<16;w2++) s2 = fmaf(mem_s[u*16+w2], mem_s[u*16+w2], s2);
    mnorm_s[u] = sqrtf(s2) + EPSC;
  }
  __syncthreads();

  if (u < 64){
    int r = u>>4, n = u&15;
    float dot = 0.f;
    #pragma unroll
    for (int w2=0;w2<16;w2++) dot = fmaf(rkey_s[r*16+w2], mem_s[n*16+w2], dot);
    float score = rbeta_s[r]*dot/(rknorm_s[r]*mnorm_s[n]);
    float mx = score;
    #pragma unroll
    for (int m2=1;m2<16;m2<<=1) mx = fmaxf(mx, __shfl_xor(mx, m2, 64));
    float p  = __expf(score - mx);
    float ps = p;
    #pragma unroll
    for (int m2=1;m2<16;m2<<=1) ps += __shfl_xor(ps, m2, 64);
    float wcr = p/ps;
    float m0 = mode_s[r*3+0], m1 = mode_s[r*3+1], m22 = mode_s[r*3+2];
    float mm = fmaxf(m0, fmaxf(m1, m22));
    float e0 = __expf(m0-mm), e1 = __expf(m1-mm), e2 = __expf(m22-mm);
    wlr_s[u] = (e2/(e0+e1+e2))*wcr;
  }
  __syncthreads();

  if (u < 64){
    int r = u>>4, w2 = u&15;
    float rv = 0.f;
    #pragma unroll
    for (int n2=0;n2<16;n2++) rv = fmaf(wlr_s[r*16+n2], mem_s[n2*16+w2], rv);
    rv_s[u] = rv;
  }
  __syncthreads();

  if (u < 20){
    float a = out_b[u];
    #pragma unroll
    for (int k=0;k<64;k++) a = fmaf(h_s[k],  out_W[u*128+k],    a);
    #pragma unroll
    for (int k=0;k<64;k++) a = fmaf(rv_s[k], out_W[u*128+64+k], a);
    x4b_s[u] = a;
  }
  __syncthreads();
  if (u < 20){
    float a = lin_b[u];
    #pragma unroll
    for (int k=0;k<20;k++) a = fmaf(x4_s[k],  lin_W[u*40+k],    a);
    #pragma unroll
    for (int k=0;k<20;k++) a = fmaf(x4b_s[k], lin_W[u*40+20+k], a);
    x5_s[u] = fmaxf(a, 0.f);
  }
  __syncthreads();

  for (int a = u; a < 1000; a += 256){
    float acc = act_b[a];
    #pragma unroll
    for (int jx=0;jx<20;jx++) acc = fmaf(x5_s[jx], act_W[a*20+jx], acc);
    out[a] = acc;
  }
}

extern "C" void kernel_launch(void* const* d_in, const int* in_sizes, int n_in,
                              void* d_out, int out_size, void* d_ws, size_t ws_size,
                              hipStream_t stream) {
  const int*   x         = (const int*)  d_in[0];
  const float* emb       = (const float*)d_in[1];
  const float* lstm_Wih  = (const float*)d_in[2];
  const float* lstm_Whh  = (const float*)d_in[3];
  const float* lstm_bih  = (const float*)d_in[4];
  const float* lstm_bhh  = (const float*)d_in[5];
  const float* ctrl_Wih  = (const float*)d_in[6];
  const float* ctrl_bih  = (const float*)d_in[8];
  const float* ctrl_bhh  = (const float*)d_in[9];
  const float* w_alloc_W = (const float*)d_in[14];
  const float* w_alloc_b = (const float*)d_in[15];
  const float* w_gate_W  = (const float*)d_in[16];
  const float* w_gate_b  = (const float*)d_in[17];
  const float* w_erase_W = (const float*)d_in[18];
  const float* w_erase_b = (const float*)d_in[19];
  const float* w_add_W   = (const float*)d_in[20];
  const float* w_add_b   = (const float*)d_in[21];
  const float* r_key_W   = (const float*)d_in[22];
  const float* r_key_b   = (const float*)d_in[23];
  const float* r_beta_W  = (const float*)d_in[24];
  const float* r_beta_b  = (const float*)d_in[25];
  const float* r_mode_W  = (const float*)d_in[28];
  const float* r_mode_b  = (const float*)d_in[29];
  const float* out_W     = (const float*)d_in[30];
  const float* out_b     = (const float*)d_in[31];
  const float* lin_W     = (const float*)d_in[32];
  const float* lin_b     = (const float*)d_in[33];
  const float* act_W     = (const float*)d_in[34];
  const float* act_b     = (const float*)d_in[35];

  float* spart   = (float*)d_ws;                     // NCHUNK*20 floats (16B-aligned)
  int*   counter = (int*)(spart + NCHUNK*20);

  hipMemsetAsync(counter, 0, sizeof(int), stream);   // graph memset node
  k_all<<<NBLK, 256, 0, stream>>>(x, emb, lstm_Wih, lstm_bih, lstm_bhh, lstm_Whh,
      ctrl_Wih, ctrl_bih, ctrl_bhh,
      w_alloc_W, w_alloc_b, w_gate_W, w_gate_b,
      w_erase_W, w_erase_b, w_add_W, w_add_b,
      r_key_W, r_key_b, r_beta_W, r_beta_b,
      r_mode_W, r_mode_b, out_W, out_b, lin_W, lin_b,
      act_W, act_b, spart, counter, (float*)d_out);
}

// Round 17
// 26.950 us; speedup vs baseline: 1.7362x; 1.7362x over previous
//
#include <hip/hip_runtime.h>
#include <hip/hip_bf16.h>
#include <math.h>

#define SEQ 8192
#define NSYM 1000000
#define EPSC 1e-6f

#define NCHUNK 1024
#define KEEPG 2             // kept groups per chunk (8 steps)
#define WARMG 4             // warmup groups (16 steps), clamped at t=0
#define NG 6                // static groups processed per block (24 steps)

typedef float v2f __attribute__((ext_vector_type(2)));
typedef float v4f __attribute__((ext_vector_type(4)));

__device__ __forceinline__ float rcp_(float x){ return __builtin_amdgcn_rcpf(x); }
__device__ __forceinline__ float exp2f_(float x){ return __builtin_amdgcn_exp2f(x); }
__device__ __forceinline__ float sigf(float x){ return rcp_(1.f + exp2f_(-1.44269504f*x)); }
__device__ __forceinline__ float tanhf_(float x){
  float e = exp2f_(2.88539008f*fabsf(x));
  float t = 1.f - 2.f*rcp_(e + 1.f);
  return copysignf(t, x);
}
__device__ __forceinline__ float softplusf_(float x){
  return fmaxf(x, 0.f) + log1pf(__expf(-fabsf(x)));
}
__device__ __forceinline__ float rdlane(float v, int lane){
  return __builtin_bit_cast(float, __builtin_amdgcn_readlane(__builtin_bit_cast(int, v), lane));
}
// exchange with lane^32 partner — ds_bpermute-backed shfl (proven R2/R7/R10/R12/R14/R15)
__device__ __forceinline__ float xchg32(float v){
  return __shfl_xor(v, 32, 64);
}

// ---------------- Kernel 1: fused gate-preactivation + chunked LSTM scan ----------------
// Chunk b keeps steps [b*8, b*8+8), warming up from zero state 16 steps
// earlier, clamped at t=0. Every block statically processes NG=6 groups
// starting at g0 = max(0, 2b-4); keep is a per-group predicate
// (clamped chunks scan a few extra groups after the kept region — s is
// already final, harmless). A is computed INLINE (emb gather + Wih matvec,
// same op order as the old k_pre -> bit-identical); no A2 buffer.
__global__ __launch_bounds__(64) void k_scan(
    const int* __restrict__ x, const float* __restrict__ emb,
    const float* __restrict__ Wih, const float* __restrict__ bih,
    const float* __restrict__ bhh, const float* __restrict__ Whh,
    float* __restrict__ spart){
  const int u    = threadIdx.x;
  const int b    = blockIdx.x;             // chunk id
  const int half = u >> 5;
  const int j    = u & 31;
  const int jj   = (j < 20) ? j : 0;

  const int rowA = half ? (20+jj) : jj;        // f : i
  const int rowB = half ? (60+jj) : (40+jj);   // o : g

  const int kept0 = b*KEEPG;                                // first kept group
  const int g0    = (kept0 >= WARMG) ? (kept0 - WARMG) : 0; // clamped start
  const int t0    = g0*4;                                   // first step

  __shared__ int   xs_i[NG*4];
  __shared__ float xe_s[NG*4][20];        // rows 16B-aligned (80B stride)

  if (u < NG*4) xs_i[u] = x[t0 + u];
  __syncthreads();
  #pragma unroll
  for (int it=0; it<8; it++){             // 480 elements / 64 lanes
    int idx = u + it*64;
    if (idx < NG*4*20){
      int r = idx/20, k = idx%20;
      int sym = xs_i[r];
      xe_s[r][k] = (sym == NSYM) ? 0.f : emb[(size_t)sym*20 + k];
    }
  }

  // paired weights: recurrent {A,B} quarters and input-side {A,B}
  v2f W0[5], W1[5], W2[5], W3[5], WIF[20];
  #pragma unroll
  for (int k=0;k<5;k++){
    W0[k] = (v2f){Whh[rowA*20+k   ], Whh[rowB*20+k   ]};
    W1[k] = (v2f){Whh[rowA*20+5+k ], Whh[rowB*20+5+k ]};
    W2[k] = (v2f){Whh[rowA*20+10+k], Whh[rowB*20+10+k]};
    W3[k] = (v2f){Whh[rowA*20+15+k], Whh[rowB*20+15+k]};
  }
  #pragma unroll
  for (int k=0;k<20;k++) WIF[k] = (v2f){Wih[rowA*20+k], Wih[rowB*20+k]};
  const v2f bAB = (v2f){bih[rowA]+bhh[rowA], bih[rowB]+bhh[rowB]};

  __syncthreads();

  // inline A: AG[g][tl] = {A(t,rowA), A(t,rowB)} — bias + ascending-k fma
  v2f AG[NG][4];
  #pragma unroll
  for (int g=0; g<NG; g++){
    #pragma unroll
    for (int tl=0; tl<4; tl++){
      v2f acc = bAB;
      #pragma unroll
      for (int q=0;q<5;q++){
        const float4 xr = *(const float4*)&xe_s[g*4+tl][q*4];
        acc = __builtin_elementwise_fma((v2f){xr.x,xr.x}, WIF[q*4+0], acc);
        acc = __builtin_elementwise_fma((v2f){xr.y,xr.y}, WIF[q*4+1], acc);
        acc = __builtin_elementwise_fma((v2f){xr.z,xr.z}, WIF[q*4+2], acc);
        acc = __builtin_elementwise_fma((v2f){xr.w,xr.w}, WIF[q*4+3], acc);
      }
      AG[g][tl] = acc;
    }
  }

  const float mtr = half ? -1.44269504f : 2.88539008f;
  float h=0.f, c=0.f, s=0.f;

  auto stepf = [&](v2f pab, float kp){
    v2f A0 = pab, A1 = (v2f){0.f,0.f}, A2v = (v2f){0.f,0.f}, A3 = (v2f){0.f,0.f};
    #pragma unroll
    for (int k=0;k<5;k++){
      float h0 = rdlane(h, 32+k);
      float h1 = rdlane(h, 37+k);
      float h2 = rdlane(h, 42+k);
      float h3 = rdlane(h, 47+k);
      A0  = __builtin_elementwise_fma((v2f){h0,h0}, W0[k], A0);
      A1  = __builtin_elementwise_fma((v2f){h1,h1}, W1[k], A1);
      A2v = __builtin_elementwise_fma((v2f){h2,h2}, W2[k], A2v);
      A3  = __builtin_elementwise_fma((v2f){h3,h3}, W3[k], A3);
    }
    v2f S = (A0+A1) + (A2v+A3);
    float s0 = sigf(S.x);               // halfA: sig(i)   halfB: sig(f)
    float xx = half ? S.y : fabsf(S.y);
    float e  = exp2f_(mtr*xx);          // halfA: e^{2|g|}  halfB: e^{-o}
    float z  = rcp_(1.f + e);
    float u2 = half ? z                                  // sig(o)
                    : copysignf(fmaf(-2.f, z, 1.f), S.y); // tanh(g)
    float send = s0 * u2;               // halfA payload: sig(i)*tanh(g)
    float recv = xchg32(send);
    c = fmaf(s0, c, recv);              // halfB: c = sig(f)*c + sig(i)*tanh(g)
    h = u2 * tanhf_(c);                 // halfB: h = sig(o)*tanh(c)
    s = fmaf(kp, h, s);                 // accumulate only in kept region
  };

  #pragma unroll
  for (int g=0; g<NG; g++){
    int ag = g0 + g;
    float kp = (ag >= kept0 && ag < kept0+KEEPG) ? 1.f : 0.f;
    stepf(AG[g][0], kp);
    stepf(AG[g][1], kp);
    stepf(AG[g][2], kp);
    stepf(AG[g][3], kp);
  }

  if (u >= 32 && u < 52) spart[b*20 + (u-32)] = s;   // s lives in upper half
}

// ---------------- Kernel 2: reduce + DNC step + MLP + action layer (fused) ----------------
__global__ __launch_bounds__(256) void k_dnc(
    const float* __restrict__ spart,
    const float* __restrict__ ctrl_Wih, const float* __restrict__ ctrl_bih, const float* __restrict__ ctrl_bhh,
    const float* __restrict__ w_alloc_W, const float* __restrict__ w_alloc_b,
    const float* __restrict__ w_gate_W,  const float* __restrict__ w_gate_b,
    const float* __restrict__ w_erase_W, const float* __restrict__ w_erase_b,
    const float* __restrict__ w_add_W,   const float* __restrict__ w_add_b,
    const float* __restrict__ r_key_W,   const float* __restrict__ r_key_b,
    const float* __restrict__ r_beta_W,  const float* __restrict__ r_beta_b,
    const float* __restrict__ r_mode_W,  const float* __restrict__ r_mode_b,
    const float* __restrict__ out_W,     const float* __restrict__ out_b,
    const float* __restrict__ lin_W,     const float* __restrict__ lin_b,
    const float* __restrict__ act_W,     const float* __restrict__ act_b,
    float* __restrict__ out){
  const int u = threadIdx.x;

  __shared__ float part_s[256][20];
  __shared__ float x4_s[20], h_s[64], rkey_s[64], rbeta_s[4], rknorm_s[4];
  __shared__ float erase_s[16], add_s[16], mode_s[12], wlw_s[16];
  __shared__ float mem_s[256], mnorm_s[16], wlr_s[64], rv_s[64], x4b_s[20], x5_s[20];
  __shared__ float scal_s[2];

  // ---- phase 1: each thread sums 4 whole chunks via 20 independent float4 loads ----
  {
    const v4f* sp4 = (const v4f*)spart;      // chunk c = v4f [c*5 .. c*5+5)
    v4f acc[5];
    #pragma unroll
    for (int q=0;q<5;q++) acc[q] = (v4f){0.f,0.f,0.f,0.f};
    #pragma unroll
    for (int cc=0;cc<4;cc++){
      #pragma unroll
      for (int q=0;q<5;q++) acc[q] += sp4[(u*4+cc)*5 + q];
    }
    #pragma unroll
    for (int q=0;q<5;q++){
      part_s[u][q*4+0] = acc[q].x;
      part_s[u][q*4+1] = acc[q].y;
      part_s[u][q*4+2] = acc[q].z;
      part_s[u][q*4+3] = acc[q].w;
    }
  }
  __syncthreads();
  // ---- phase 2: 20 lanes sum 256 LDS values each ----
  if (u < 20){
    float t = 0.f;
    #pragma unroll
    for (int k=0;k<256;k++) t += part_s[k][u];
    x4_s[u] = t;
  }
  __syncthreads();

  // ---- controller LSTMCell: input = cat(x4, zeros(64)); h0=c0=0 (wave 0) ----
  if (u < 64){
    float gi = ctrl_bih[u]      + ctrl_bhh[u];
    float gG = ctrl_bih[128+u]  + ctrl_bhh[128+u];
    float go = ctrl_bih[192+u]  + ctrl_bhh[192+u];
    #pragma unroll
    for (int k=0;k<20;k++){
      float xk = x4_s[k];
      gi = fmaf(xk, ctrl_Wih[(0  +u)*84+k], gi);
      gG = fmaf(xk, ctrl_Wih[(128+u)*84+k], gG);
      go = fmaf(xk, ctrl_Wih[(192+u)*84+k], go);
    }
    float cc = sigf(gi)*tanhf_(gG);
    float hh = sigf(go)*tanhf_(cc);
    hh = fminf(fmaxf(hh, -20.f), 20.f);
    h_s[u] = hh;
  }
  __syncthreads();

  // ---- head linears over h, spread across the 4 waves ----
  if (u < 64){                                   // wave 0: rkey (64 dots)
    float d = r_key_b[u];
    #pragma unroll
    for (int k=0;k<64;k++) d = fmaf(h_s[k], r_key_W[u*64+k], d);
    rkey_s[u] = tanhf_(d);
  } else if (u >= 64 && u < 80){                 // wave 1: erase
    int e = u-64; float d = w_erase_b[e];
    #pragma unroll
    for (int k=0;k<64;k++) d = fmaf(h_s[k], w_erase_W[e*64+k], d);
    erase_s[e] = sigf(d);
  } else if (u >= 128 && u < 144){               // wave 2: add
    int a = u-128; float d = w_add_b[a];
    #pragma unroll
    for (int k=0;k<64;k++) d = fmaf(h_s[k], w_add_W[a*64+k], d);
    add_s[a] = tanhf_(d);
  } else if (u >= 144 && u < 156){               // wave 2: mode
    int m = u-144; float d = r_mode_b[m];
    #pragma unroll
    for (int k=0;k<64;k++) d = fmaf(h_s[k], r_mode_W[m*64+k], d);
    mode_s[m] = d;
  } else if (u >= 192 && u < 196){               // wave 3: rbeta
    int r = u-192; float d = r_beta_b[r];
    #pragma unroll
    for (int k=0;k<64;k++) d = fmaf(h_s[k], r_beta_W[r*64+k], d);
    rbeta_s[r] = softplusf_(d);
  } else if (u == 196){                          // wave 3: alloc gate
    float d = w_alloc_b[0];
    #pragma unroll
    for (int k=0;k<64;k++) d = fmaf(h_s[k], w_alloc_W[k], d);
    scal_s[0] = sigf(d);
  } else if (u == 197){                          // wave 3: write gate
    float d = w_gate_b[0];
    #pragma unroll
    for (int k=0;k<64;k++) d = fmaf(h_s[k], w_gate_W[k], d);
    scal_s[1] = sigf(d);
  }
  __syncthreads();

  const float alloc_gate = scal_s[0], write_gate = scal_s[1];

  // usage==0 -> alloc[i]=(1-eps)*eps^i (stable top_k, identity perm); content = 1/16 exactly
  if (u < 16){
    float cp = 1.f;
    for (int i2=0;i2<u;i2++) cp *= EPSC;
    float alloc = (1.f-EPSC)*cp;
    wlw_s[u] = write_gate*(alloc_gate*alloc + (1.f-alloc_gate)*0.0625f);
  }
  if (u >= 32 && u < 36){                        // rknorm (needs rkey_s)
    int r = u-32;
    float s2 = 0.f;
    #pragma unroll
    for (int w=0;w<16;w++) s2 = fmaf(rkey_s[r*16+w], rkey_s[r*16+w], s2);
    rknorm_s[r] = sqrtf(s2) + EPSC;
  }
  __syncthreads();

  {                                              // mem: one element per thread
    int n = u>>4, w = u&15;
    float wlw = wlw_s[n];
    mem_s[u] = 1e-6f*(1.f - wlw*erase_s[w]) + wlw*add_s[w];
  }
  __syncthreads();
  if (u < 16){
    float s2 = 0.f;
    #pragma unroll
    for (int w=0;w<16;w++) s2 = fmaf(mem_s[u*16+w], mem_s[u*16+w], s2);
    mnorm_s[u] = sqrtf(s2) + EPSC;
  }
  __syncthreads();

  // read content weights + mode blend (fw=bw=0 since link==0, wl_r_prev==0) — wave 0
  if (u < 64){
    int r = u>>4, n = u&15;
    float dot = 0.f;
    #pragma unroll
    for (int w=0;w<16;w++) dot = fmaf(rkey_s[r*16+w], mem_s[n*16+w], dot);
    float score = rbeta_s[r]*dot/(rknorm_s[r]*mnorm_s[n]);
    float mx = score;
    #pragma unroll
    for (int m2=1;m2<16;m2<<=1) mx = fmaxf(mx, __shfl_xor(mx, m2, 64));
    float p  = __expf(score - mx);
    float ps = p;
    #pragma unroll
    for (int m2=1;m2<16;m2<<=1) ps += __shfl_xor(ps, m2, 64);
    float wcr = p/ps;
    float m0 = mode_s[r*3+0], m1 = mode_s[r*3+1], m22 = mode_s[r*3+2];
    float mm = fmaxf(m0, fmaxf(m1, m22));
    float e0 = __expf(m0-mm), e1 = __expf(m1-mm), e2 = __expf(m22-mm);
    wlr_s[u] = (e2/(e0+e1+e2))*wcr;
  }
  __syncthreads();

  if (u < 64){
    int r = u>>4, w = u&15;
    float rv = 0.f;
    #pragma unroll
    for (int n2=0;n2<16;n2++) rv = fmaf(wlr_s[r*16+n2], mem_s[n2*16+w], rv);
    rv_s[u] = rv;
  }
  __syncthreads();

  if (u < 20){
    float a = out_b[u];
    #pragma unroll
    for (int k=0;k<64;k++) a = fmaf(h_s[k],  out_W[u*128+k],    a);
    #pragma unroll
    for (int k=0;k<64;k++) a = fmaf(rv_s[k], out_W[u*128+64+k], a);
    x4b_s[u] = a;
  }
  __syncthreads();
  if (u < 20){
    float a = lin_b[u];
    #pragma unroll
    for (int k=0;k<20;k++) a = fmaf(x4_s[k],  lin_W[u*40+k],    a);
    #pragma unroll
    for (int k=0;k<20;k++) a = fmaf(x4b_s[k], lin_W[u*40+20+k], a);
    x5_s[u] = fmaxf(a, 0.f);
  }
  __syncthreads();

  // ---- final action layer: all 256 threads ----
  for (int a = u; a < 1000; a += 256){
    float acc = act_b[a];
    #pragma unroll
    for (int jx=0;jx<20;jx++) acc = fmaf(x5_s[jx], act_W[a*20+jx], acc);
    out[a] = acc;
  }
}

extern "C" void kernel_launch(void* const* d_in, const int* in_sizes, int n_in,
                              void* d_out, int out_size, void* d_ws, size_t ws_size,
                              hipStream_t stream) {
  const int*   x         = (const int*)  d_in[0];
  const float* emb       = (const float*)d_in[1];
  const float* lstm_Wih  = (const float*)d_in[2];
  const float* lstm_Whh  = (const float*)d_in[3];
  const float* lstm_bih  = (const float*)d_in[4];
  const float* lstm_bhh  = (const float*)d_in[5];
  const float* ctrl_Wih  = (const float*)d_in[6];
  const float* ctrl_bih  = (const float*)d_in[8];
  const float* ctrl_bhh  = (const float*)d_in[9];
  const float* w_alloc_W = (const float*)d_in[14];
  const float* w_alloc_b = (const float*)d_in[15];
  const float* w_gate_W  = (const float*)d_in[16];
  const float* w_gate_b  = (const float*)d_in[17];
  const float* w_erase_W = (const float*)d_in[18];
  const float* w_erase_b = (const float*)d_in[19];
  const float* w_add_W   = (const float*)d_in[20];
  const float* w_add_b   = (const float*)d_in[21];
  const float* r_key_W   = (const float*)d_in[22];
  const float* r_key_b   = (const float*)d_in[23];
  const float* r_beta_W  = (const float*)d_in[24];
  const float* r_beta_b  = (const float*)d_in[25];
  const float* r_mode_W  = (const float*)d_in[28];
  const float* r_mode_b  = (const float*)d_in[29];
  const float* out_W     = (const float*)d_in[30];
  const float* out_b     = (const float*)d_in[31];
  const float* lin_W     = (const float*)d_in[32];
  const float* lin_b     = (const float*)d_in[33];
  const float* act_W     = (const float*)d_in[34];
  const float* act_b     = (const float*)d_in[35];

  float* spart = (float*)d_ws;                        // NCHUNK*20 floats (16B-aligned)

  k_scan<<<NCHUNK, 64, 0, stream>>>(x, emb, lstm_Wih, lstm_bih, lstm_bhh, lstm_Whh, spart);
  k_dnc<<<1, 256, 0, stream>>>(spart,
      ctrl_Wih, ctrl_bih, ctrl_bhh,
      w_alloc_W, w_alloc_b, w_gate_W, w_gate_b,
      w_erase_W, w_erase_b, w_add_W, w_add_b,
      r_key_W, r_key_b, r_beta_W, r_beta_b,
      r_mode_W, r_mode_b, out_W, out_b, lin_W, lin_b,
      act_W, act_b, (float*)d_out);
}